// Round 4
// baseline (293.776 us; speedup 1.0000x reference)
//
#include <hip/hip_runtime.h>

// N=64, C=M=128, F=2048
//   scores[n,c,m] = sum_f X[n,c,f]*A[c,m,f];  W = softmax_m(scores)
//   out[n,c,f]    = sum_m W[n,c,m]*X[n,m,f]
// v4: all global traffic as contiguous 1KB wave-loads (DRAM-efficiency fix),
// VGPR-mediated staging with fp32->bf16 convert, register prefetch pipeline,
// XOR-swizzled LDS chunks. No K-split: scores fp32 (4MB) + separate softmax.

typedef __attribute__((ext_vector_type(8))) short bf16x8;
typedef __attribute__((ext_vector_type(4))) float f32x4;

static __device__ __forceinline__ unsigned f2bf_pk(float a, float b) {
    unsigned ua = __float_as_uint(a);
    unsigned ub = __float_as_uint(b);
    ua = (ua + 0x7FFFu + ((ua >> 16) & 1u)) >> 16;
    ub = (ub + 0x7FFFu + ((ub >> 16) & 1u)) >> 16;
    return ua | (ub << 16);
}

// ---------------- Kernel 1: scores (fp32 out) ----------------------------
// grid 256 = c(128) x mhalf(2); block 512 (8 waves); tile n64 x m64, K=2048
// 8 iters of BK=256 (1KB contiguous per row-load). LDS 64KB -> 1 block/CU.
__global__ __launch_bounds__(512, 2) void k_scores(const float* __restrict__ X,
                                                   const float* __restrict__ A,
                                                   float* __restrict__ Sc) {
    __shared__ short Xb[64 * 256];   // 32 KB bf16, 512B rows, 16B chunks swizzled
    __shared__ short Ab[64 * 256];   // 32 KB bf16

    const int c  = blockIdx.x >> 1;
    const int mh = blockIdx.x & 1;
    const int t = threadIdx.x;
    const int l = t & 63;
    const int w = t >> 6;            // 0..7
    const int l15 = l & 15;
    const int lg = l >> 4;
    const int nw = (w & 1) * 32;     // wave n-base
    const int mw = (w >> 1) * 16;    // wave m-base (local, 0..48)
    const int q = l >> 1;            // 16B-bf16 chunk index 0..31
    const int h = l & 1;             // half-chunk

    const float* Xg = X + ((size_t)(w * 8) * 128 + c) * 2048 + l * 4;
    const float* Ag = A + ((size_t)c * 128 + mh * 64 + w * 8) * 2048 + l * 4;

    float4 xr[8], ar[8];
    f32x4 acc[2];
    acc[0] = (f32x4)0.0f; acc[1] = (f32x4)0.0f;

    // prefetch iter 0
#pragma unroll
    for (int r = 0; r < 8; ++r) xr[r] = *(const float4*)(Xg + (size_t)r * (128 * 2048));
#pragma unroll
    for (int r = 0; r < 8; ++r) ar[r] = *(const float4*)(Ag + (size_t)r * 2048);

    for (int it = 0; it < 8; ++it) {
        if (it) __syncthreads();                 // prev frag reads done
        // convert + LDS write (8 rows each of X and A per wave)
#pragma unroll
        for (int r = 0; r < 8; ++r) {
            const int row = w * 8 + r;
            const int s = (q & 24) | ((q ^ (row & 7)) & 7);
            *(uint2*)&Xb[row * 256 + s * 8 + h * 4] =
                make_uint2(f2bf_pk(xr[r].x, xr[r].y), f2bf_pk(xr[r].z, xr[r].w));
            *(uint2*)&Ab[row * 256 + s * 8 + h * 4] =
                make_uint2(f2bf_pk(ar[r].x, ar[r].y), f2bf_pk(ar[r].z, ar[r].w));
        }
        __syncthreads();                         // tiles ready
        if (it < 7) {                            // prefetch next iter (overlaps MFMA)
            const int f = (it + 1) * 256;
#pragma unroll
            for (int r = 0; r < 8; ++r) xr[r] = *(const float4*)(Xg + (size_t)r * (128 * 2048) + f);
#pragma unroll
            for (int r = 0; r < 8; ++r) ar[r] = *(const float4*)(Ag + (size_t)r * 2048 + f);
        }
        // compute: 8 k-steps of K=32
#pragma unroll
        for (int ks = 0; ks < 8; ++ks) {
            const int qq = ks * 4 + lg;
            const int r0 = nw + l15, r1 = nw + 16 + l15, rb = mw + l15;
            bf16x8 a0 = *(const bf16x8*)&Xb[r0 * 256 + ((qq & 24) | ((qq ^ (r0 & 7)) & 7)) * 8];
            bf16x8 a1 = *(const bf16x8*)&Xb[r1 * 256 + ((qq & 24) | ((qq ^ (r1 & 7)) & 7)) * 8];
            bf16x8 b  = *(const bf16x8*)&Ab[rb * 256 + ((qq & 24) | ((qq ^ (rb & 7)) & 7)) * 8];
            acc[0] = __builtin_amdgcn_mfma_f32_16x16x32_bf16(a0, b, acc[0], 0, 0, 0);
            acc[1] = __builtin_amdgcn_mfma_f32_16x16x32_bf16(a1, b, acc[1], 0, 0, 0);
        }
    }

    // write fp32 scores: Sc[n][c][m]
#pragma unroll
    for (int i = 0; i < 2; ++i) {
        const int n = nw + 16 * i + lg * 4;
        const int m = mh * 64 + mw + l15;
        float* o = Sc + ((size_t)n * 128 + c) * 128 + m;
#pragma unroll
        for (int r = 0; r < 4; ++r) o[(size_t)r * 16384] = acc[i][r];
    }
}

// ---------------- Kernel 2: softmax -> W bf16 ----------------------------
// grid 2048 x 256: one wave per (n,c) row of 128 fp32 scores
__global__ __launch_bounds__(256) void k_softmax(const float* __restrict__ Sc,
                                                 unsigned int* __restrict__ Wout) {
    const int t = threadIdx.x;
    const int l = t & 63;
    const int row = blockIdx.x * 4 + (t >> 6);   // n*128 + c

    float2 v = *(const float2*)(Sc + (size_t)row * 128 + 2 * l);
    float mx = fmaxf(v.x, v.y);
#pragma unroll
    for (int d = 1; d < 64; d <<= 1) mx = fmaxf(mx, __shfl_xor(mx, d, 64));
    float e0 = __expf(v.x - mx), e1 = __expf(v.y - mx);
    float sm = e0 + e1;
#pragma unroll
    for (int d = 1; d < 64; d <<= 1) sm += __shfl_xor(sm, d, 64);
    const float inv = 1.0f / sm;
    Wout[(size_t)row * 64 + l] = f2bf_pk(e0 * inv, e1 * inv);
}

// ---------------- Kernel 3: combine --------------------------------------
// grid 512 = n(64) x ftile(8); block 512 (8 waves); tile c128 x f256, K=m=128
// 4 iters of BK=32 m-rows (1KB contiguous X rows). LDS 64KB -> 2 blocks/CU.
__global__ __launch_bounds__(512, 4) void k_combine(const float* __restrict__ X,
                                                    const unsigned short* __restrict__ W,
                                                    float* __restrict__ out) {
    __shared__ unsigned short Wl[128 * 128]; // 32 KB bf16, 16B chunks swizzled
    __shared__ float Xs[32 * 256];           // 32 KB fp32 [m][f], linear

    const int n  = blockIdx.x >> 3;
    const int f0 = (blockIdx.x & 7) * 256;
    const int t = threadIdx.x;
    const int l = t & 63;
    const int w = t >> 6;
    const int l15 = l & 15;
    const int lg = l >> 4;
    const int wc = (w & 1) * 64;
    const int wf = (w >> 1) * 64;

    // load W[n] (32 KB) into regs
    const uint4* Wg = (const uint4*)(W + (size_t)n * 16384);
    uint4 wr[4];
#pragma unroll
    for (int ro = 0; ro < 4; ++ro) wr[ro] = Wg[ro * 512 + t];

    // prefetch X chunk 0
    float4 xr[4];
#pragma unroll
    for (int ii = 0; ii < 4; ++ii)
        xr[ii] = *(const float4*)(X + ((size_t)n * 128 + w * 4 + ii) * 2048 + f0 + l * 4);

    f32x4 acc[4][4];
#pragma unroll
    for (int i = 0; i < 4; ++i)
#pragma unroll
        for (int j = 0; j < 4; ++j) acc[i][j] = (f32x4)0.0f;

    for (int it = 0; it < 4; ++it) {
        if (it == 0) {
            // write W to LDS, swizzled 16B chunks
#pragma unroll
            for (int ro = 0; ro < 4; ++ro) {
                const int flat = ro * 512 + t;
                const int r = flat >> 4;
                const int qq = flat & 15;
                const int s = (qq & 8) | ((qq ^ (r & 7)) & 7);
                *(uint4*)&Wl[r * 128 + s * 8] = wr[ro];
            }
        } else {
            __syncthreads();                     // prev Xs reads done
        }
        // write X chunk to LDS (linear fp32)
#pragma unroll
        for (int ii = 0; ii < 4; ++ii)
            *(float4*)&Xs[(w * 4 + ii) * 256 + l * 4] = xr[ii];
        __syncthreads();
        if (it < 3) {                            // prefetch next chunk
            const int m0 = (it + 1) * 32;
#pragma unroll
            for (int ii = 0; ii < 4; ++ii)
                xr[ii] = *(const float4*)(X + ((size_t)n * 128 + m0 + w * 4 + ii) * 2048 + f0 + l * 4);
        }
        // fragments + MFMA
        bf16x8 a[4], b[4];
#pragma unroll
        for (int i = 0; i < 4; ++i) {
            const int cr = wc + 16 * i + l15;
            const int q2 = it * 4 + lg;
            const int s = (q2 & 8) | ((q2 ^ (cr & 7)) & 7);
            a[i] = *(const bf16x8*)&Wl[cr * 128 + s * 8];
        }
#pragma unroll
        for (int j = 0; j < 4; ++j) {
            const int col = wf + 16 * j + l15;
            float v[8];
#pragma unroll
            for (int rr = 0; rr < 8; ++rr) v[rr] = Xs[(lg * 8 + rr) * 256 + col];
            union { bf16x8 bv; unsigned u[4]; } r_;
            r_.u[0] = f2bf_pk(v[0], v[1]);
            r_.u[1] = f2bf_pk(v[2], v[3]);
            r_.u[2] = f2bf_pk(v[4], v[5]);
            r_.u[3] = f2bf_pk(v[6], v[7]);
            b[j] = r_.bv;
        }
#pragma unroll
        for (int i = 0; i < 4; ++i)
#pragma unroll
            for (int j = 0; j < 4; ++j)
                acc[i][j] = __builtin_amdgcn_mfma_f32_16x16x32_bf16(a[i], b[j], acc[i][j], 0, 0, 0);
    }

#pragma unroll
    for (int i = 0; i < 4; ++i) {
        const int c0 = wc + 16 * i + lg * 4;
#pragma unroll
        for (int j = 0; j < 4; ++j) {
            const int f = f0 + wf + 16 * j + l15;
            float* o = out + ((size_t)n * 128 + c0) * 2048 + f;
#pragma unroll
            for (int r = 0; r < 4; ++r) o[(size_t)r * 2048] = acc[i][j][r];
        }
    }
}

extern "C" void kernel_launch(void* const* d_in, const int* in_sizes, int n_in,
                              void* d_out, int out_size, void* d_ws, size_t ws_size,
                              hipStream_t stream) {
    const float* X = (const float*)d_in[0];   // [64,128,2048]
    const float* A = (const float*)d_in[1];   // [128,128,2048]
    float* out = (float*)d_out;               // [64,128,2048]

    float* Sc = (float*)d_ws;                                  // 4 MiB fp32 scores
    unsigned short* Wb = (unsigned short*)((char*)d_ws + (size_t)64 * 128 * 128 * 4); // 2 MiB

    k_scores<<<dim3(256), dim3(512), 0, stream>>>(X, A, Sc);
    k_softmax<<<dim3(2048), dim3(256), 0, stream>>>(Sc, (unsigned int*)Wb);
    k_combine<<<dim3(512), dim3(512), 0, stream>>>(X, Wb, out);
}